// Round 8
// baseline (189.603 us; speedup 1.0000x reference)
//
#include <hip/hip_runtime.h>
#include <cstdint>
#include <cstddef>

// YOLO NMS for batch 0 of preds (32, 84, 8400) fp32.
// Reference: conf=max(scores), cls=argmax, top_k(1024) by masked conf,
// pairwise IOU on class-offset xyxy boxes, greedy sequential suppression,
// top 300 kept rows -> (300,6) [x1,y1,x2,y2,conf,cls], rest zeros.
//
// Structure: 4 small kernels (graph-captured). Cooperative single-kernel
// fusion was tried (R6) and regressed badly: grid.sync() ~35us each on
// gfx950 vs ~3us kernel boundaries. Do not re-fuse. Scatter kernel was
// folded into k_supmat's per-block gather (R8): every supmat block needs
// all 1024 boxes in LDS anyway, so it gathers via rank[] directly.

#define NA    8400
#define NCLS  80
#define NTOP  1024
#define NDET  300
#define CONF_T 0.25f
#define IOU_T  0.45f
#define MAXWH  7680.0f

#define NSLICE 25          // j-dimension slices for rank computation
#define SLICEW 336         // 25 * 336 = 8400, multiple of 4 for uint4

// ws layout (bytes)
#define OFF_KEY   0        // u32[8400]  sortable key-hi (desc conf)
#define OFF_CLS   33600    // f32[8400]  class as float
#define OFF_CONF  67200    // f32[8400]  masked conf
#define OFF_SCONF 100800   // f32[1024]  sorted (top-1024) conf
#define OFF_SX1   104896
#define OFF_SY1   108992
#define OFF_SX2   113088
#define OFF_SY2   117184
#define OFF_SCLS  121280
#define OFF_SUP   125376   // u64[1024*16] suppression bitmask rows
#define OFF_RANK  256448   // u32[8400]  rank accumulator (atomicAdd)
// total ws usage: 290048 bytes

typedef unsigned long long u64;
typedef unsigned int u32;

// swizzled LDS index: breaks stride-64 (16-way) bank conflicts in k_supmat
__device__ __forceinline__ int sw(int j) { return j + (j >> 6); }

__device__ __forceinline__ u32 f2mono(float f) {
    u32 u = __float_as_uint(f);
    return u ^ ((u & 0x80000000u) ? 0xFFFFFFFFu : 0x80000000u);
}
__device__ __forceinline__ float mono2f(u32 m) {
    u32 u = (m & 0x80000000u) ? (m ^ 0x80000000u) : ~m;
    return __uint_as_float(u);
}
// broadcast lane g's u64 to all lanes (g uniform; source lanes always active)
__device__ __forceinline__ u64 rl64(u64 v, int g) {
    u32 lo = (u32)__builtin_amdgcn_readlane((int)(u32)v, g);
    u32 hi = (u32)__builtin_amdgcn_readlane((int)(u32)(v >> 32), g);
    return ((u64)hi << 32) | lo;
}

// ---- K1: conf/argmax over 8 parallel class-slices, LDS combine ----
// 132 blocks x 512 thr: q=tid>>6 handles classes [q*10, q*10+10) for anchor
// a = blk*64 + (tid&63). Packed u64 (mono<<32 | 255-cls): max == larger
// conf, tie -> smaller class (== first-occurrence argmax).
__global__ __launch_bounds__(512) void k_confcls(const float* __restrict__ pred,
                                                 u32* __restrict__ key,
                                                 float* __restrict__ clsf,
                                                 float* __restrict__ conf,
                                                 u32* __restrict__ rank)
{
    __shared__ u64 pk[8][64];
    int tid = threadIdx.x;
    int q = tid >> 6, t = tid & 63;
    int a = blockIdx.x * 64 + t;
    u64 pv = 0ULL;
    if (a < NA) {
        const float* s = pred + (size_t)(4 + q * 10) * NA;
        float best = s[a];
        int bc = q * 10;
#pragma unroll
        for (int c = 1; c < 10; ++c) {
            float v = s[(size_t)c * NA + a];
            if (v > best) { best = v; bc = q * 10 + c; }   // strict > == first occurrence
        }
        pv = ((u64)f2mono(best) << 32) | (u32)(255 - bc);
    }
    pk[q][t] = pv;
    __syncthreads();
    if (q == 0 && a < NA) {
        u64 mm = pk[0][t];
#pragma unroll
        for (int r = 1; r < 8; ++r) { u64 v = pk[r][t]; if (v > mm) mm = v; }
        float best = mono2f((u32)(mm >> 32));
        int bc = 255 - (int)(mm & 0xFFu);
        float m = (best > CONF_T) ? best : -1.0f;   // masked_conf
        key[a]  = ~f2mono(m);                       // ascending key == descending conf
        clsf[a] = (float)bc;
        conf[a] = m;
        rank[a] = 0u;                               // zero accumulator
    }
}

// ------- K2: partial rank over one j-slice (exact top_k tie order) -------
__global__ __launch_bounds__(256) void k_rank_partial(const u32* __restrict__ key,
                                                      u32* __restrict__ rank)
{
    __shared__ __align__(16) u32 kh[SLICEW];
    int tid = threadIdx.x;
    int s   = blockIdx.y;               // which j-slice
    int jb  = s * SLICEW;
    for (int k = tid; k < SLICEW; k += 256) kh[k] = key[jb + k];
    __syncthreads();

    int a = blockIdx.x * 256 + tid;
    if (a >= NA) return;

    u64 myk = (((u64)key[a]) << 32) | (u32)a;
    u32 r = 0;
    const uint4* kv4 = (const uint4*)kh;
#pragma unroll 4
    for (int j4 = 0; j4 < SLICEW / 4; ++j4) {
        uint4 kk = kv4[j4];              // uniform address -> LDS broadcast
        u32 j = (u32)jb + (u32)j4 * 4u;
        r += ((((u64)kk.x) << 32) | (j + 0u)) < myk;
        r += ((((u64)kk.y) << 32) | (j + 1u)) < myk;
        r += ((((u64)kk.z) << 32) | (j + 2u)) < myk;
        r += ((((u64)kk.w) << 32) | (j + 3u)) < myk;
    }
    atomicAdd(&rank[a], r);             // 25 adds per address total: low contention
}

// ------ K3: gather top-1024 via rank + 1024x1024 IOU -> suppression ------
// 64 blocks x 256 thr. Every block gathers all 1024 sorted boxes into LDS
// directly from pred/rank (this IS the scatter, done locally — saves a
// kernel). Block 0 additionally writes the wsf sorted arrays for k_nms_out.
// Float op order matches ref exactly: xyxy = xy -/+ wh*0.5, then +cls*MAXWH,
// area from offset boxes. Thread handles row i = gid>>4, chunk l = gid&15.
__global__ __launch_bounds__(256) void k_supmat(const float* __restrict__ pred,
                                                const u32* __restrict__ rank,
                                                const float* __restrict__ clsf,
                                                const float* __restrict__ conf,
                                                float* __restrict__ wsf,
                                                u64* __restrict__ sup)
{
#pragma clang fp contract(off)
    __shared__ float4 obox[NTOP + 16];
    __shared__ float  oar[NTOP + 16];
    int tid = threadIdx.x;
    bool b0 = (blockIdx.x == 0);
    for (int a = tid; a < NA; a += 256) {
        u32 r = rank[a];
        if (r < NTOP) {
            float x = pred[a], y = pred[NA + a];
            float w = pred[2 * NA + a], h = pred[3 * NA + a];
            float cls = clsf[a];
            float hw = w * 0.5f, hh = h * 0.5f;
            float x1 = x - hw, y1 = y - hh, x2 = x + hw, y2 = y + hh;
            float off = cls * MAXWH;                  // ref: b + c*MAX_WH
            float ox1 = x1 + off, oy1 = y1 + off;
            float ox2 = x2 + off, oy2 = y2 + off;
            int si = sw((int)r);
            obox[si] = make_float4(ox1, oy1, ox2, oy2);
            oar[si]  = (ox2 - ox1) * (oy2 - oy1);     // area from offset boxes
            if (b0) {                                 // sorted arrays for k_nms_out
                wsf[OFF_SCONF / 4 + r] = conf[a];
                wsf[OFF_SX1  / 4 + r] = x1;
                wsf[OFF_SY1  / 4 + r] = y1;
                wsf[OFF_SX2  / 4 + r] = x2;
                wsf[OFF_SY2  / 4 + r] = y2;
                wsf[OFF_SCLS / 4 + r] = cls;
            }
        }
    }
    __syncthreads();

    int gid = blockIdx.x * 256 + tid;            // 64 blocks x 256 = 16384
    int i = gid >> 4;                            // row
    int l = gid & 15;                            // u64 chunk
    int si = sw(i);
    float4 bb = obox[si];
    float  ba = oar[si];
    u64 bits = 0ULL;
    int j0 = l << 6;
#pragma unroll 4
    for (int jj = 0; jj < 64; ++jj) {
        int j = j0 + jj;
        int sj = sw(j);
        float4 ob = obox[sj];
        float xx1 = fmaxf(bb.x, ob.x);
        float yy1 = fmaxf(bb.y, ob.y);
        float xx2 = fminf(bb.z, ob.z);
        float yy2 = fminf(bb.w, ob.w);
        float w  = fmaxf(xx2 - xx1, 0.0f);       // clip(rb-lt, 0)
        float hh = fmaxf(yy2 - yy1, 0.0f);
        float inter = w * hh;
        float denom = ba + oar[sj] - inter + 1e-7f;  // ref assoc order
        bool s = (j > i) && ((inter / denom) > IOU_T);
        bits |= ((u64)s) << jj;
    }
    sup[(size_t)i * 16 + l] = bits;
}

// -------- K4: LDS-staged serial greedy suppression + emit top-300 ---------
// 1024 threads (16 waves) so the 128 KB global->LDS staging has 4x the
// outstanding loads of a 256-thr block. Chain runs in wave 0 only.
// Key fact: a row's keep-bit is immutable once the chain passes it (sup rows
// only set bits j>i), so per 64-row group g the scalar chain over the 8 KB
// diagonal blocks (tg) yields the final fired mask, and keep updates are a
// post-hoc parallel AND-reduction. No register arrays => no scratch spills.
__global__ __launch_bounds__(1024) void k_nms_out(const float* __restrict__ wsf,
                                                  const u64* __restrict__ sup,
                                                  float* __restrict__ out)
{
    __shared__ u64 lsup[NTOP * 16];   // 128 KB, row-major suppression matrix
    __shared__ u64 tg[16 * 64];       // 8 KB diagonal blocks: tg[g*64+ii] = sup[(g*64+ii)][g]
    __shared__ u64 lkeep[64];
    __shared__ u64 kc[16];
    __shared__ u32 pcs[16];
    int tid  = threadIdx.x;
    int lane = tid & 63;
    int wv   = tid >> 6;

    // stage sup -> LDS (coalesced b128, 16 waves) + extract diagonal blocks
    {
        const uint4* gs = (const uint4*)sup;
        uint4* lv = (uint4*)lsup;
        for (int idx = tid; idx < NTOP * 8; idx += 1024) {
            uint4 v = gs[idx];
            lv[idx] = v;
            int row = idx >> 3;            // 8 uint4 per row
            int c   = (idx & 7) * 2;       // chunks c (v.xy), c+1 (v.zw)
            int g   = row >> 6;
            if (c == g)     tg[(g << 6) + (row & 63)] = (((u64)v.y) << 32) | v.x;
            if (c + 1 == g) tg[(g << 6) + (row & 63)] = (((u64)v.w) << 32) | v.z;
        }
    }

    // keep0 = sorted_conf > CONF_T: one conf per thread, one ballot per wave
    u64 bl = __ballot(wsf[OFF_SCONF / 4 + tid] > CONF_T);
    if (lane == 0) kc[wv] = bl;
    __syncthreads();

    if (wv == 0) {                       // wave 0: the serial chain
        int l   = lane & 15;             // keep chunk owned by this lane
        int rep = lane >> 4;             // replica 0..3 (rows strided by 4)
        u64 keep = kc[l];                // 4 replicas of each chunk
        for (int g = 0; g < 16; ++g) {
            // current full keep chunk g = AND of its 4 replicas
            u64 scur = rl64(keep, g) & rl64(keep, 16 + g) &
                       rl64(keep, 32 + g) & rl64(keep, 48 + g);
            u64 rgv = tg[(g << 6) + lane];     // lane ii holds rg of row g*64+ii
            // scalar chain, 64 steps; readlanes are chain-independent
#pragma unroll
            for (int ii = 0; ii < 64; ++ii) {
                u64 rg  = rl64(rgv, ii);
                u64 sel = 0ULL - ((scur >> ii) & 1ULL);
                scur &= ~(rg & sel);
            }
            // mass update: fired == scur; replica rep applies rows 4b+rep
#pragma unroll 4
            for (int b = 0; b < 16; ++b) {
                int i_loc = (b << 2) + rep;
                u64 rl = lsup[(((g << 6) + i_loc) << 4) + l];  // base+lane: conflict-free
                u64 m  = 0ULL - ((scur >> i_loc) & 1ULL);
                keep &= ~(rl & m);
            }
        }
        lkeep[lane] = keep;
    }
    __syncthreads();

    if (tid < 16) {
        u64 kk = lkeep[tid] & lkeep[16 + tid] & lkeep[32 + tid] & lkeep[48 + tid];
        kc[tid]  = kk;
        pcs[tid] = (u32)__popcll(kk);
    }
    __syncthreads();

    if (tid < NDET) {
        int acc = 0, chunk = -1, off = 0;
#pragma unroll
        for (int c = 0; c < 16; ++c) {
            int p = (int)pcs[c];
            if (chunk < 0 && tid < acc + p) { chunk = c; off = tid - acc; }
            acc += p;
        }
        float o0 = 0.f, o1 = 0.f, o2 = 0.f, o3 = 0.f, o4 = 0.f, o5 = 0.f;
        if (chunk >= 0) {   // tid-th surviving box in sorted order
            u64 mk = kc[chunk];
            for (int q = 0; q < off; ++q) mk &= mk - 1ULL;
            int p = chunk * 64 + __builtin_ctzll(mk);
            o0 = wsf[OFF_SX1  / 4 + p];
            o1 = wsf[OFF_SY1  / 4 + p];
            o2 = wsf[OFF_SX2  / 4 + p];
            o3 = wsf[OFF_SY2  / 4 + p];
            o4 = wsf[OFF_SCONF / 4 + p];   // kept => conf > CONF_T, row valid
            o5 = wsf[OFF_SCLS / 4 + p];
        }
        out[tid * 6 + 0] = o0; out[tid * 6 + 1] = o1; out[tid * 6 + 2] = o2;
        out[tid * 6 + 3] = o3; out[tid * 6 + 4] = o4; out[tid * 6 + 5] = o5;
    }
}

extern "C" void kernel_launch(void* const* d_in, const int* in_sizes, int n_in,
                              void* d_out, int out_size, void* d_ws, size_t ws_size,
                              hipStream_t stream)
{
    const float* preds = (const float*)d_in[0];   // (32,84,8400); only batch 0 used
    char* ws = (char*)d_ws;
    u32* key    = (u32*)(ws + OFF_KEY);
    float* clsf = (float*)(ws + OFF_CLS);
    float* conf = (float*)(ws + OFF_CONF);
    float* wsf  = (float*)ws;
    u64* sup    = (u64*)(ws + OFF_SUP);
    u32* rank   = (u32*)(ws + OFF_RANK);
    float* out  = (float*)d_out;

    hipLaunchKernelGGL(k_confcls,      dim3(132),        dim3(512),  0, stream, preds, key, clsf, conf, rank);
    hipLaunchKernelGGL(k_rank_partial, dim3(33, NSLICE), dim3(256),  0, stream, key, rank);
    hipLaunchKernelGGL(k_supmat,       dim3(64),         dim3(256),  0, stream, preds, rank, clsf, conf, wsf, sup);
    hipLaunchKernelGGL(k_nms_out,      dim3(1),          dim3(1024), 0, stream, wsf, sup, out);
}

// Round 9
// 168.942 us; speedup vs baseline: 1.1223x; 1.1223x over previous
//
#include <hip/hip_runtime.h>
#include <cstdint>
#include <cstddef>

// YOLO NMS for batch 0 of preds (32, 84, 8400) fp32.
// Reference: conf=max(scores), cls=argmax, top_k(1024) by masked conf,
// pairwise IOU on class-offset xyxy boxes, greedy sequential suppression,
// top 300 kept rows -> (300,6) [x1,y1,x2,y2,conf,cls], rest zeros.
//
// Structure: 5 small kernels (graph-captured) — R7-measured baseline (170us)
// with rank sliced 50-way. Cooperative single-kernel fusion regressed (R6:
// grid.sync ~35us each on gfx950). Folding scatter into supmat's 64 blocks
// regressed (R8: 64x redundant gather > 1 launch boundary). Do not re-fuse.

#define NA    8400
#define NCLS  80
#define NTOP  1024
#define NDET  300
#define CONF_T 0.25f
#define IOU_T  0.45f
#define MAXWH  7680.0f

#define NSLICE 50          // j-dimension slices for rank computation
#define SLICEW 168         // 50 * 168 = 8400, multiple of 4 for uint4

// ws layout (bytes)
#define OFF_KEY   0        // u32[8400]  sortable key-hi (desc conf)
#define OFF_CLS   33600    // f32[8400]  class as float
#define OFF_CONF  67200    // f32[8400]  masked conf
#define OFF_SCONF 100800   // f32[1024]  sorted (top-1024) conf
#define OFF_SX1   104896
#define OFF_SY1   108992
#define OFF_SX2   113088
#define OFF_SY2   117184
#define OFF_SCLS  121280
#define OFF_SUP   125376   // u64[1024*16] suppression bitmask rows
#define OFF_RANK  256448   // u32[8400]  rank accumulator (atomicAdd)
// total ws usage: 290048 bytes

typedef unsigned long long u64;
typedef unsigned int u32;

// swizzled LDS index: breaks stride-64 (16-way) bank conflicts in k_supmat
__device__ __forceinline__ int sw(int j) { return j + (j >> 6); }

__device__ __forceinline__ u32 f2mono(float f) {
    u32 u = __float_as_uint(f);
    return u ^ ((u & 0x80000000u) ? 0xFFFFFFFFu : 0x80000000u);
}
__device__ __forceinline__ float mono2f(u32 m) {
    u32 u = (m & 0x80000000u) ? (m ^ 0x80000000u) : ~m;
    return __uint_as_float(u);
}
// broadcast lane g's u64 to all lanes (g uniform; source lanes always active)
__device__ __forceinline__ u64 rl64(u64 v, int g) {
    u32 lo = (u32)__builtin_amdgcn_readlane((int)(u32)v, g);
    u32 hi = (u32)__builtin_amdgcn_readlane((int)(u32)(v >> 32), g);
    return ((u64)hi << 32) | lo;
}

// ---- K1: conf/argmax over 8 parallel class-slices, LDS combine ----
// 66 blocks x 1024 thr: q=tid>>7 handles classes [q*10, q*10+10) for anchor
// a = blk*128 + (tid&127). Packed u64 (mono<<32 | 255-cls): max == larger
// conf, tie -> smaller class (== first-occurrence argmax).
__global__ __launch_bounds__(1024) void k_confcls(const float* __restrict__ pred,
                                                  u32* __restrict__ key,
                                                  float* __restrict__ clsf,
                                                  float* __restrict__ conf,
                                                  u32* __restrict__ rank)
{
    __shared__ u64 pk[8][128];
    int tid = threadIdx.x;
    int q = tid >> 7, t = tid & 127;
    int a = blockIdx.x * 128 + t;
    u64 pv = 0ULL;
    if (a < NA) {
        const float* s = pred + (size_t)(4 + q * 10) * NA;
        float best = s[a];
        int bc = q * 10;
#pragma unroll
        for (int c = 1; c < 10; ++c) {
            float v = s[(size_t)c * NA + a];
            if (v > best) { best = v; bc = q * 10 + c; }   // strict > == first occurrence
        }
        pv = ((u64)f2mono(best) << 32) | (u32)(255 - bc);
    }
    pk[q][t] = pv;
    __syncthreads();
    if (q == 0 && a < NA) {
        u64 mm = pk[0][t];
#pragma unroll
        for (int r = 1; r < 8; ++r) { u64 v = pk[r][t]; if (v > mm) mm = v; }
        float best = mono2f((u32)(mm >> 32));
        int bc = 255 - (int)(mm & 0xFFu);
        float m = (best > CONF_T) ? best : -1.0f;   // masked_conf
        key[a]  = ~f2mono(m);                       // ascending key == descending conf
        clsf[a] = (float)bc;
        conf[a] = m;
        rank[a] = 0u;                               // zero accumulator
    }
}

// ------- K2a: partial rank over one j-slice (exact top_k tie order) -------
__global__ __launch_bounds__(256) void k_rank_partial(const u32* __restrict__ key,
                                                      u32* __restrict__ rank)
{
    __shared__ __align__(16) u32 kh[SLICEW];
    int tid = threadIdx.x;
    int s   = blockIdx.y;               // which j-slice
    int jb  = s * SLICEW;
    for (int k = tid; k < SLICEW; k += 256) kh[k] = key[jb + k];
    __syncthreads();

    int a = blockIdx.x * 256 + tid;
    if (a >= NA) return;

    u64 myk = (((u64)key[a]) << 32) | (u32)a;
    u32 r = 0;
    const uint4* kv4 = (const uint4*)kh;
#pragma unroll 4
    for (int j4 = 0; j4 < SLICEW / 4; ++j4) {
        uint4 kk = kv4[j4];              // uniform address -> LDS broadcast
        u32 j = (u32)jb + (u32)j4 * 4u;
        r += ((((u64)kk.x) << 32) | (j + 0u)) < myk;
        r += ((((u64)kk.y) << 32) | (j + 1u)) < myk;
        r += ((((u64)kk.z) << 32) | (j + 2u)) < myk;
        r += ((((u64)kk.w) << 32) | (j + 3u)) < myk;
    }
    atomicAdd(&rank[a], r);             // 50 adds per address total: low contention
}

// ---------------- K2b: scatter top-1024 into sorted order ----------------
__global__ __launch_bounds__(256) void k_scatter(const float* __restrict__ pred,
                                                 const u32* __restrict__ rank,
                                                 const float* __restrict__ clsf,
                                                 const float* __restrict__ conf,
                                                 float* __restrict__ wsf)
{
    int a = blockIdx.x * 256 + threadIdx.x;
    if (a >= NA) return;
    u32 r = rank[a];
    if (r < NTOP) {
#pragma clang fp contract(off)
        float x = pred[0 * NA + a], y = pred[1 * NA + a];
        float w = pred[2 * NA + a], h = pred[3 * NA + a];
        float hw = w * 0.5f, hh = h * 0.5f;     // xywh -> xyxy, ref op order
        wsf[OFF_SCONF / 4 + r] = conf[a];
        wsf[OFF_SX1  / 4 + r] = x - hw;
        wsf[OFF_SY1  / 4 + r] = y - hh;
        wsf[OFF_SX2  / 4 + r] = x + hw;
        wsf[OFF_SY2  / 4 + r] = y + hh;
        wsf[OFF_SCLS / 4 + r] = clsf[a];
    }
}

// ---------------- K3: 1024x1024 IOU -> suppression bitmask ----------------
// 64 blocks x 256 thr; thread handles row i = gid>>4, chunk l = gid&15.
// Boxes staged as float4 (1 ds_read_b128/j); swizzle keeps conflicts <=2-way.
__global__ __launch_bounds__(256) void k_supmat(const float* __restrict__ wsf,
                                                u64* __restrict__ sup)
{
#pragma clang fp contract(off)
    __shared__ float4 obox[NTOP + 16];
    __shared__ float  oar[NTOP + 16];
    int tid = threadIdx.x;
    for (int k = tid; k < NTOP; k += 256) {
        float cls = wsf[OFF_SCLS / 4 + k];
        float off = cls * MAXWH;                 // ref: b + c*MAX_WH
        float x1 = wsf[OFF_SX1 / 4 + k] + off;
        float y1 = wsf[OFF_SY1 / 4 + k] + off;
        float x2 = wsf[OFF_SX2 / 4 + k] + off;
        float y2 = wsf[OFF_SY2 / 4 + k] + off;
        int si = sw(k);
        obox[si] = make_float4(x1, y1, x2, y2);
        oar[si]  = (x2 - x1) * (y2 - y1);        // area from offset boxes (as ref)
    }
    __syncthreads();

    int gid = blockIdx.x * 256 + tid;            // 64 blocks x 256 = 16384
    int i = gid >> 4;                            // row
    int l = gid & 15;                            // u64 chunk
    int si = sw(i);
    float4 bb = obox[si];
    float  ba = oar[si];
    u64 bits = 0ULL;
    int j0 = l << 6;
#pragma unroll 4
    for (int jj = 0; jj < 64; ++jj) {
        int j = j0 + jj;
        int sj = sw(j);
        float4 ob = obox[sj];
        float xx1 = fmaxf(bb.x, ob.x);
        float yy1 = fmaxf(bb.y, ob.y);
        float xx2 = fminf(bb.z, ob.z);
        float yy2 = fminf(bb.w, ob.w);
        float w  = fmaxf(xx2 - xx1, 0.0f);       // clip(rb-lt, 0)
        float hh = fmaxf(yy2 - yy1, 0.0f);
        float inter = w * hh;
        float denom = ba + oar[sj] - inter + 1e-7f;  // ref assoc order
        bool s = (j > i) && ((inter / denom) > IOU_T);
        bits |= ((u64)s) << jj;
    }
    sup[(size_t)i * 16 + l] = bits;
}

// -------- K4: LDS-staged serial greedy suppression + emit top-300 ---------
// 1024 threads (16 waves) so the 128 KB global->LDS staging has 4x the
// outstanding loads of a 256-thr block. Chain runs in wave 0 only.
// Key fact: a row's keep-bit is immutable once the chain passes it (sup rows
// only set bits j>i), so per 64-row group g the scalar chain over the 8 KB
// diagonal blocks (tg) yields the final fired mask, and keep updates are a
// post-hoc parallel AND-reduction. No register arrays => no scratch spills.
__global__ __launch_bounds__(1024) void k_nms_out(const float* __restrict__ wsf,
                                                  const u64* __restrict__ sup,
                                                  float* __restrict__ out)
{
    __shared__ u64 lsup[NTOP * 16];   // 128 KB, row-major suppression matrix
    __shared__ u64 tg[16 * 64];       // 8 KB diagonal blocks: tg[g*64+ii] = sup[(g*64+ii)][g]
    __shared__ u64 lkeep[64];
    __shared__ u64 kc[16];
    __shared__ u32 pcs[16];
    int tid  = threadIdx.x;
    int lane = tid & 63;
    int wv   = tid >> 6;

    // stage sup -> LDS (coalesced b128, 16 waves) + extract diagonal blocks
    {
        const uint4* gs = (const uint4*)sup;
        uint4* lv = (uint4*)lsup;
        for (int idx = tid; idx < NTOP * 8; idx += 1024) {
            uint4 v = gs[idx];
            lv[idx] = v;
            int row = idx >> 3;            // 8 uint4 per row
            int c   = (idx & 7) * 2;       // chunks c (v.xy), c+1 (v.zw)
            int g   = row >> 6;
            if (c == g)     tg[(g << 6) + (row & 63)] = (((u64)v.y) << 32) | v.x;
            if (c + 1 == g) tg[(g << 6) + (row & 63)] = (((u64)v.w) << 32) | v.z;
        }
    }

    // keep0 = sorted_conf > CONF_T: one conf per thread, one ballot per wave
    u64 bl = __ballot(wsf[OFF_SCONF / 4 + tid] > CONF_T);
    if (lane == 0) kc[wv] = bl;
    __syncthreads();

    if (wv == 0) {                       // wave 0: the serial chain
        int l   = lane & 15;             // keep chunk owned by this lane
        int rep = lane >> 4;             // replica 0..3 (rows strided by 4)
        u64 keep = kc[l];                // 4 replicas of each chunk
        for (int g = 0; g < 16; ++g) {
            // current full keep chunk g = AND of its 4 replicas
            u64 scur = rl64(keep, g) & rl64(keep, 16 + g) &
                       rl64(keep, 32 + g) & rl64(keep, 48 + g);
            u64 rgv = tg[(g << 6) + lane];     // lane ii holds rg of row g*64+ii
            // scalar chain, 64 steps; readlanes are chain-independent
#pragma unroll
            for (int ii = 0; ii < 64; ++ii) {
                u64 rg  = rl64(rgv, ii);
                u64 sel = 0ULL - ((scur >> ii) & 1ULL);
                scur &= ~(rg & sel);
            }
            // mass update: fired == scur; replica rep applies rows 4b+rep
#pragma unroll 4
            for (int b = 0; b < 16; ++b) {
                int i_loc = (b << 2) + rep;
                u64 rl = lsup[(((g << 6) + i_loc) << 4) + l];  // base+lane: conflict-free
                u64 m  = 0ULL - ((scur >> i_loc) & 1ULL);
                keep &= ~(rl & m);
            }
        }
        lkeep[lane] = keep;
    }
    __syncthreads();

    if (tid < 16) {
        u64 kk = lkeep[tid] & lkeep[16 + tid] & lkeep[32 + tid] & lkeep[48 + tid];
        kc[tid]  = kk;
        pcs[tid] = (u32)__popcll(kk);
    }
    __syncthreads();

    if (tid < NDET) {
        int acc = 0, chunk = -1, off = 0;
#pragma unroll
        for (int c = 0; c < 16; ++c) {
            int p = (int)pcs[c];
            if (chunk < 0 && tid < acc + p) { chunk = c; off = tid - acc; }
            acc += p;
        }
        float o0 = 0.f, o1 = 0.f, o2 = 0.f, o3 = 0.f, o4 = 0.f, o5 = 0.f;
        if (chunk >= 0) {   // tid-th surviving box in sorted order
            u64 mk = kc[chunk];
            for (int q = 0; q < off; ++q) mk &= mk - 1ULL;
            int p = chunk * 64 + __builtin_ctzll(mk);
            o0 = wsf[OFF_SX1  / 4 + p];
            o1 = wsf[OFF_SY1  / 4 + p];
            o2 = wsf[OFF_SX2  / 4 + p];
            o3 = wsf[OFF_SY2  / 4 + p];
            o4 = wsf[OFF_SCONF / 4 + p];   // kept => conf > CONF_T, row valid
            o5 = wsf[OFF_SCLS / 4 + p];
        }
        out[tid * 6 + 0] = o0; out[tid * 6 + 1] = o1; out[tid * 6 + 2] = o2;
        out[tid * 6 + 3] = o3; out[tid * 6 + 4] = o4; out[tid * 6 + 5] = o5;
    }
}

extern "C" void kernel_launch(void* const* d_in, const int* in_sizes, int n_in,
                              void* d_out, int out_size, void* d_ws, size_t ws_size,
                              hipStream_t stream)
{
    const float* preds = (const float*)d_in[0];   // (32,84,8400); only batch 0 used
    char* ws = (char*)d_ws;
    u32* key    = (u32*)(ws + OFF_KEY);
    float* clsf = (float*)(ws + OFF_CLS);
    float* conf = (float*)(ws + OFF_CONF);
    float* wsf  = (float*)ws;
    u64* sup    = (u64*)(ws + OFF_SUP);
    u32* rank   = (u32*)(ws + OFF_RANK);
    float* out  = (float*)d_out;

    hipLaunchKernelGGL(k_confcls,      dim3(66),         dim3(1024), 0, stream, preds, key, clsf, conf, rank);
    hipLaunchKernelGGL(k_rank_partial, dim3(33, NSLICE), dim3(256),  0, stream, key, rank);
    hipLaunchKernelGGL(k_scatter,      dim3(33),         dim3(256),  0, stream, preds, rank, clsf, conf, wsf);
    hipLaunchKernelGGL(k_supmat,       dim3(64),         dim3(256),  0, stream, wsf, sup);
    hipLaunchKernelGGL(k_nms_out,      dim3(1),          dim3(1024), 0, stream, wsf, sup, out);
}